// Round 1
// baseline (1488.050 us; speedup 1.0000x reference)
//
#include <hip/hip_runtime.h>

#define NNODES 40000
#define DFEAT  128
#define NEDGE  640000

// ---------------- CSR build ----------------

__global__ __launch_bounds__(256) void count_rows_k(const int* __restrict__ rows,
                                                    int* __restrict__ cnt, int E) {
    int i = blockIdx.x * 256 + threadIdx.x;
    if (i < E) atomicAdd(&cnt[rows[i]], 1);
}

__global__ __launch_bounds__(1024) void exscan_k(const int* __restrict__ cnt,
                                                 int* __restrict__ rp,
                                                 int* __restrict__ cur) {
    __shared__ int buf[1024];
    __shared__ int carry_s;
    int tid = threadIdx.x;
    if (tid == 0) carry_s = 0;
    __syncthreads();
    for (int base = 0; base < NNODES; base += 1024) {
        int i = base + tid;
        int v = (i < NNODES) ? cnt[i] : 0;
        buf[tid] = v;
        __syncthreads();
        for (int off = 1; off < 1024; off <<= 1) {
            int t = (tid >= off) ? buf[tid - off] : 0;
            __syncthreads();
            buf[tid] += t;
            __syncthreads();
        }
        int incl = buf[tid];
        int carry = carry_s;
        if (i < NNODES) { rp[i] = carry + incl - v; cur[i] = carry + incl - v; }
        __syncthreads();
        if (tid == 1023) carry_s = carry + buf[1023];
        __syncthreads();
    }
    if (tid == 0) rp[NNODES] = carry_s;
}

__global__ __launch_bounds__(256) void scatter_k(const int* __restrict__ rows,
                                                 const int* __restrict__ cols,
                                                 const float* __restrict__ w,
                                                 int* __restrict__ cur,
                                                 int2* __restrict__ csr, int E) {
    int e = blockIdx.x * 256 + threadIdx.x;
    if (e < E) {
        int r = rows[e];
        int p = atomicAdd(&cur[r], 1);
        csr[p] = make_int2(cols[e], __float_as_int(w[e]));
    }
}

// ---------------- dense x@W for 3 weight mats ----------------

__global__ __launch_bounds__(256) void gemm3_k(const float* __restrict__ x,
                                               const float* __restrict__ Wa,
                                               const float* __restrict__ Wb,
                                               const float* __restrict__ Wc,
                                               float* __restrict__ oa,
                                               float* __restrict__ ob,
                                               float* __restrict__ oc) {
    __shared__ float xs[32][132];   // +4 pad: stride%32 = 4 -> conflict-free row broadcast
    long b0 = (long)blockIdx.x * 32;
    const float4* xg = (const float4*)(x + b0 * 128);
    for (int i = threadIdx.x; i < 1024; i += 256) {
        int r = i >> 5, cq = i & 31;
        *(float4*)&xs[r][cq * 4] = xg[i];
    }
    __syncthreads();
    int row = threadIdx.x >> 3, cg = threadIdx.x & 7;
    int c0 = cg * 16;
    const float* xr = xs[row];
    const float* Ws[3] = {Wa, Wb, Wc};
    float*       Os[3] = {oa, ob, oc};
#pragma unroll
    for (int m = 0; m < 3; ++m) {
        const float* W = Ws[m];
        float acc[16];
#pragma unroll
        for (int i = 0; i < 16; ++i) acc[i] = 0.f;
        for (int k = 0; k < 128; ++k) {
            float xv = xr[k];
            const float4* wk = (const float4*)(W + k * 128 + c0);
            float4 a4 = wk[0], b4 = wk[1], c4 = wk[2], d4 = wk[3];
            acc[0]  = fmaf(xv, a4.x, acc[0]);  acc[1]  = fmaf(xv, a4.y, acc[1]);
            acc[2]  = fmaf(xv, a4.z, acc[2]);  acc[3]  = fmaf(xv, a4.w, acc[3]);
            acc[4]  = fmaf(xv, b4.x, acc[4]);  acc[5]  = fmaf(xv, b4.y, acc[5]);
            acc[6]  = fmaf(xv, b4.z, acc[6]);  acc[7]  = fmaf(xv, b4.w, acc[7]);
            acc[8]  = fmaf(xv, c4.x, acc[8]);  acc[9]  = fmaf(xv, c4.y, acc[9]);
            acc[10] = fmaf(xv, c4.z, acc[10]); acc[11] = fmaf(xv, c4.w, acc[11]);
            acc[12] = fmaf(xv, d4.x, acc[12]); acc[13] = fmaf(xv, d4.y, acc[13]);
            acc[14] = fmaf(xv, d4.z, acc[14]); acc[15] = fmaf(xv, d4.w, acc[15]);
        }
        float* o = Os[m] + (b0 + row) * 128 + c0;
        ((float4*)o)[0] = make_float4(acc[0],  acc[1],  acc[2],  acc[3]);
        ((float4*)o)[1] = make_float4(acc[4],  acc[5],  acc[6],  acc[7]);
        ((float4*)o)[2] = make_float4(acc[8],  acc[9],  acc[10], acc[11]);
        ((float4*)o)[3] = make_float4(acc[12], acc[13], acc[14], acc[15]);
    }
}

// ---------------- SpMM: out[r] = alpha * sum_e w_e * in[col_e] + beta * prev[r] ----------------

__global__ __launch_bounds__(256) void spmm_k(const int* __restrict__ rp,
                                              const int2* __restrict__ csr,
                                              const float* __restrict__ in,
                                              const float* __restrict__ prev,
                                              float* __restrict__ out,
                                              float alpha, float beta) {
    int r = blockIdx.x * 4 + (threadIdx.x >> 6);
    int lane = threadIdx.x & 63;
    int s = rp[r], e1 = rp[r + 1];
    float ax = 0.f, ay = 0.f;
    for (int e = s; e < e1; ++e) {
        int2 cw = csr[e];
        float wv = __int_as_float(cw.y);
        float2 v = ((const float2*)(in + (long)cw.x * 128))[lane];
        ax = fmaf(wv, v.x, ax);
        ay = fmaf(wv, v.y, ay);
    }
    float2 res;
    if (prev) {
        float2 pv = ((const float2*)(prev + (long)r * 128))[lane];
        res.x = alpha * ax + beta * pv.x;
        res.y = alpha * ay + beta * pv.y;
    } else {
        res.x = alpha * ax;
        res.y = alpha * ay;
    }
    ((float2*)(out + (long)r * 128))[lane] = res;
}

// ---------------- batch stats (sum, sumsq per channel) ----------------

__global__ __launch_bounds__(256) void stats_k(const float* __restrict__ buf,
                                               float* __restrict__ sum,
                                               float* __restrict__ sumsq) {
    int c = threadIdx.x & 127, half = threadIdx.x >> 7;
    int r0 = blockIdx.x * 128;
    int rend = r0 + 128; if (rend > NNODES) rend = NNODES;
    float s = 0.f, s2 = 0.f;
    for (int r = r0 + half; r < rend; r += 2) {
        float v = buf[(long)r * 128 + c];
        s += v;
        s2 = fmaf(v, v, s2);
    }
    __shared__ float sh[256], sh2[256];
    sh[threadIdx.x] = s; sh2[threadIdx.x] = s2;
    __syncthreads();
    if (threadIdx.x < 128) {
        atomicAdd(&sum[c],   sh[c]  + sh[c + 128]);
        atomicAdd(&sumsq[c], sh2[c] + sh2[c + 128]);
    }
}

__global__ void bnfin_k(const float* __restrict__ sum, const float* __restrict__ sumsq,
                        const float* __restrict__ g0, const float* __restrict__ be0,
                        const float* __restrict__ g1, const float* __restrict__ be1,
                        const float* __restrict__ g2, const float* __restrict__ be2,
                        float* __restrict__ bn) {
    int i = threadIdx.x;
    if (i >= 384) return;
    int s = i >> 7, c = i & 127;
    float mean = sum[i] * (1.f / NNODES);
    float var  = sumsq[i] * (1.f / NNODES) - mean * mean;
    const float* g = (s == 0) ? g0 : (s == 1) ? g1 : g2;
    const float* b = (s == 0) ? be0 : (s == 1) ? be1 : be2;
    float sc = g[c] * rsqrtf(var + 1e-5f);
    bn[s * 256 + c]       = sc;
    bn[s * 256 + 128 + c] = b[c] - mean * sc;
}

// ---------------- fused BN + PReLU + concat@W_mlp + row-normalize ----------------

__global__ __launch_bounds__(256) void final_k(const float* __restrict__ org0,
                                               const float* __restrict__ p2,
                                               const float* __restrict__ n2,
                                               const float* __restrict__ bn,
                                               const float* __restrict__ prelu_w,
                                               const float* __restrict__ Wmlp,
                                               float* __restrict__ out) {
    __shared__ float v[32][388];   // 388%32=4 -> conflict-free
    long b0 = (long)blockIdx.x * 32;
    float pw = prelu_w[0];
    const float* srcs[3] = {org0, p2, n2};
#pragma unroll
    for (int s = 0; s < 3; ++s) {
        const float* src = srcs[s];
        const float4* sc4 = (const float4*)(bn + s * 256);
        const float4* sh4 = (const float4*)(bn + s * 256 + 128);
        for (int i = threadIdx.x; i < 1024; i += 256) {
            int r = i >> 5, cq = i & 31;
            float4 val = ((const float4*)(src + (b0 + r) * 128))[cq];
            float4 sc = sc4[cq], sh = sh4[cq];
            float4 o;
            o.x = fmaf(val.x, sc.x, sh.x); o.x = (o.x >= 0.f) ? o.x : pw * o.x;
            o.y = fmaf(val.y, sc.y, sh.y); o.y = (o.y >= 0.f) ? o.y : pw * o.y;
            o.z = fmaf(val.z, sc.z, sh.z); o.z = (o.z >= 0.f) ? o.z : pw * o.z;
            o.w = fmaf(val.w, sc.w, sh.w); o.w = (o.w >= 0.f) ? o.w : pw * o.w;
            *(float4*)&v[r][s * 128 + cq * 4] = o;
        }
    }
    __syncthreads();
    int row = threadIdx.x >> 3, cg = threadIdx.x & 7, c0 = cg * 16;
    const float* vr = v[row];
    float acc[16];
#pragma unroll
    for (int i = 0; i < 16; ++i) acc[i] = 0.f;
    for (int k = 0; k < 384; ++k) {
        float xv = vr[k];
        const float4* wk = (const float4*)(Wmlp + k * 128 + c0);
        float4 a4 = wk[0], b4 = wk[1], c4 = wk[2], d4 = wk[3];
        acc[0]  = fmaf(xv, a4.x, acc[0]);  acc[1]  = fmaf(xv, a4.y, acc[1]);
        acc[2]  = fmaf(xv, a4.z, acc[2]);  acc[3]  = fmaf(xv, a4.w, acc[3]);
        acc[4]  = fmaf(xv, b4.x, acc[4]);  acc[5]  = fmaf(xv, b4.y, acc[5]);
        acc[6]  = fmaf(xv, b4.z, acc[6]);  acc[7]  = fmaf(xv, b4.w, acc[7]);
        acc[8]  = fmaf(xv, c4.x, acc[8]);  acc[9]  = fmaf(xv, c4.y, acc[9]);
        acc[10] = fmaf(xv, c4.z, acc[10]); acc[11] = fmaf(xv, c4.w, acc[11]);
        acc[12] = fmaf(xv, d4.x, acc[12]); acc[13] = fmaf(xv, d4.y, acc[13]);
        acc[14] = fmaf(xv, d4.z, acc[14]); acc[15] = fmaf(xv, d4.w, acc[15]);
    }
    float ss = 0.f;
#pragma unroll
    for (int i = 0; i < 16; ++i) ss = fmaf(acc[i], acc[i], ss);
    ss += __shfl_xor(ss, 1);
    ss += __shfl_xor(ss, 2);
    ss += __shfl_xor(ss, 4);
    float inv = 1.f / fmaxf(sqrtf(ss), 1e-12f);
    float* o = out + (b0 + row) * 128 + c0;
    ((float4*)o)[0] = make_float4(acc[0] * inv,  acc[1] * inv,  acc[2] * inv,  acc[3] * inv);
    ((float4*)o)[1] = make_float4(acc[4] * inv,  acc[5] * inv,  acc[6] * inv,  acc[7] * inv);
    ((float4*)o)[2] = make_float4(acc[8] * inv,  acc[9] * inv,  acc[10] * inv, acc[11] * inv);
    ((float4*)o)[3] = make_float4(acc[12] * inv, acc[13] * inv, acc[14] * inv, acc[15] * inv);
}

// ---------------- launch ----------------

extern "C" void kernel_launch(void* const* d_in, const int* in_sizes, int n_in,
                              void* d_out, int out_size, void* d_ws, size_t ws_size,
                              hipStream_t stream) {
    const float* x       = (const float*)d_in[0];
    const int*   pos_idx = (const int*)d_in[1];
    const float* pos_w   = (const float*)d_in[2];
    const int*   neg_idx = (const int*)d_in[3];
    const float* neg_w   = (const float*)d_in[4];
    const float* W_org   = (const float*)d_in[5];
    const float* W_pos   = (const float*)d_in[6];
    const float* W_neg   = (const float*)d_in[7];
    const float* g_org   = (const float*)d_in[8];
    const float* b_org   = (const float*)d_in[9];
    const float* g_pos   = (const float*)d_in[10];
    const float* b_pos   = (const float*)d_in[11];
    const float* g_neg   = (const float*)d_in[12];
    const float* b_neg   = (const float*)d_in[13];
    const float* prelu_w = (const float*)d_in[14];
    const float* W_mlp   = (const float*)d_in[15];
    float* out = (float*)d_out;

    char* ws = (char*)d_ws;
    const size_t NB = (size_t)NNODES * 128 * 4;   // 20.48 MB per [N,128] f32 buffer
    float* org0 = (float*)(ws);
    float* p0   = (float*)(ws + NB);
    float* n0   = (float*)(ws + 2 * NB);
    float* t1   = out;                            // reuse d_out as SpMM scratch
    char* base = ws + 3 * NB;
    int2* csr_pos = (int2*)base; base += (size_t)NEDGE * 8;
    int2* csr_neg = (int2*)base; base += (size_t)NEDGE * 8;
    int* rp_pos  = (int*)base; base += 160016;
    int* rp_neg  = (int*)base; base += 160016;
    int* cur_pos = (int*)base; base += 160000;
    int* cur_neg = (int*)base; base += 160000;
    char* zbase = base;
    int* cnt_pos = (int*)base; base += 160000;
    int* cnt_neg = (int*)base; base += 160000;
    float* sums  = (float*)base; base += 1536;
    float* sumsq = (float*)base; base += 1536;
    float* bn    = (float*)base; base += 3072;

    // zero: cnt_pos, cnt_neg, sums, sumsq (contiguous)
    hipMemsetAsync(zbase, 0, 160000 * 2 + 1536 * 2, stream);

    count_rows_k<<<2500, 256, 0, stream>>>(pos_idx, cnt_pos, NEDGE);
    count_rows_k<<<2500, 256, 0, stream>>>(neg_idx, cnt_neg, NEDGE);
    exscan_k<<<1, 1024, 0, stream>>>(cnt_pos, rp_pos, cur_pos);
    exscan_k<<<1, 1024, 0, stream>>>(cnt_neg, rp_neg, cur_neg);
    scatter_k<<<2500, 256, 0, stream>>>(pos_idx, pos_idx + NEDGE, pos_w, cur_pos, csr_pos, NEDGE);
    scatter_k<<<2500, 256, 0, stream>>>(neg_idx, neg_idx + NEDGE, neg_w, cur_neg, csr_neg, NEDGE);

    gemm3_k<<<1250, 256, 0, stream>>>(x, W_org, W_pos, W_neg, org0, p0, n0);
    stats_k<<<313, 256, 0, stream>>>(org0, sums, sumsq);

    // Jacobi (a=b=1, K=3): x1 = 2*A@x0 ; x2 = 1.875*A@x1 - 1.6875*x0
    spmm_k<<<10000, 256, 0, stream>>>(rp_pos, csr_pos, p0, nullptr, t1, 2.0f, 0.f);
    spmm_k<<<10000, 256, 0, stream>>>(rp_pos, csr_pos, t1, p0, p0, 1.875f, -1.6875f);
    stats_k<<<313, 256, 0, stream>>>(p0, sums + 128, sumsq + 128);

    spmm_k<<<10000, 256, 0, stream>>>(rp_neg, csr_neg, n0, nullptr, t1, 2.0f, 0.f);
    spmm_k<<<10000, 256, 0, stream>>>(rp_neg, csr_neg, t1, n0, n0, 1.875f, -1.6875f);
    stats_k<<<313, 256, 0, stream>>>(n0, sums + 256, sumsq + 256);

    bnfin_k<<<1, 384, 0, stream>>>(sums, sumsq, g_org, b_org, g_pos, b_pos, g_neg, b_neg, bn);
    final_k<<<1250, 256, 0, stream>>>(org0, p0, n0, bn, prelu_w, W_mlp, out);

    (void)in_sizes; (void)n_in; (void)out_size; (void)ws_size;
}

// Round 2
// 565.214 us; speedup vs baseline: 2.6327x; 2.6327x over previous
//
#include <hip/hip_runtime.h>

#define NNODES 40000
#define NEDGE  640000

typedef __attribute__((ext_vector_type(8))) short bfrag;
typedef __attribute__((ext_vector_type(4))) float facc;

__device__ inline ushort f2bf(float f) {
    uint u = __float_as_uint(f);
    return (ushort)((u + 0x7FFFu + ((u >> 16) & 1u)) >> 16);
}
__device__ inline float bf2f(ushort h) {
    return __uint_as_float(((uint)h) << 16);
}

// ---------------- CSR build ----------------

__global__ __launch_bounds__(256) void count_rows_k(const int* __restrict__ rows,
                                                    int* __restrict__ cnt, int E) {
    int i = blockIdx.x * 256 + threadIdx.x;
    if (i < E) atomicAdd(&cnt[rows[i]], 1);
}

__global__ __launch_bounds__(1024) void exscan_k(const int* __restrict__ cnt,
                                                 int* __restrict__ rp,
                                                 int* __restrict__ cur) {
    __shared__ int buf[1024];
    __shared__ int carry_s;
    int tid = threadIdx.x;
    if (tid == 0) carry_s = 0;
    __syncthreads();
    for (int base = 0; base < NNODES; base += 1024) {
        int i = base + tid;
        int v = (i < NNODES) ? cnt[i] : 0;
        buf[tid] = v;
        __syncthreads();
        for (int off = 1; off < 1024; off <<= 1) {
            int t = (tid >= off) ? buf[tid - off] : 0;
            __syncthreads();
            buf[tid] += t;
            __syncthreads();
        }
        int incl = buf[tid];
        int carry = carry_s;
        if (i < NNODES) { rp[i] = carry + incl - v; cur[i] = carry + incl - v; }
        __syncthreads();
        if (tid == 1023) carry_s = carry + buf[1023];
        __syncthreads();
    }
    if (tid == 0) rp[NNODES] = carry_s;
}

__global__ __launch_bounds__(256) void scatter_k(const int* __restrict__ rows,
                                                 const int* __restrict__ cols,
                                                 const float* __restrict__ w,
                                                 int* __restrict__ cur,
                                                 int2* __restrict__ csr, int E) {
    int e = blockIdx.x * 256 + threadIdx.x;
    if (e < E) {
        int r = rows[e];
        int p = atomicAdd(&cur[r], 1);
        csr[p] = make_int2(cols[e], __float_as_int(w[e]));
    }
}

// ---------------- fp32 -> bf16 conversion ----------------

__global__ __launch_bounds__(256) void cvt_bf16_k(const float* __restrict__ in,
                                                  ushort* __restrict__ out, int n8) {
    int i = blockIdx.x * 256 + threadIdx.x;
    if (i >= n8) return;
    const float4* p = (const float4*)(in + (long)i * 8);
    float4 a = p[0], b = p[1];
    uint4 o;
    o.x = (uint)f2bf(a.x) | ((uint)f2bf(a.y) << 16);
    o.y = (uint)f2bf(a.z) | ((uint)f2bf(a.w) << 16);
    o.z = (uint)f2bf(b.x) | ((uint)f2bf(b.y) << 16);
    o.w = (uint)f2bf(b.z) | ((uint)f2bf(b.w) << 16);
    ((uint4*)out)[i] = o;
}

// ---------------- pack W [K x 128] into MFMA B-fragment order ----------------
// frag layout: elem j of lane l for (k-step ks, n-tile t):
//   B[k = ks*32 + (l>>4)*8 + j][c = (l&15) + 16*t]
// packed index: (((ks*8 + t)*64) + l)*8 + j

__global__ __launch_bounds__(256) void pack_w_k(const float* __restrict__ W,
                                                ushort* __restrict__ Bp, int K) {
    int idx = blockIdx.x * 256 + threadIdx.x;
    if (idx >= K * 128) return;
    int j = idx & 7, l = (idx >> 3) & 63, t = (idx >> 9) & 7, ks = idx >> 12;
    int k = ks * 32 + (l >> 4) * 8 + j;
    int c = (l & 15) + 16 * t;
    Bp[idx] = f2bf(W[k * 128 + c]);
}

// ---------------- MFMA GEMM: A[Mx K] bf16 @ packed W -> [M x 128] ----------------
// MODE 0: store bf16. MODE 1: fused row-L2-normalize, store fp32.

template<int K, int MODE>
__global__ __launch_bounds__(256) void mfma_gemm_k(const ushort* __restrict__ A,
                                                   const ushort* __restrict__ Bp,
                                                   void* __restrict__ Out) {
    int lane = threadIdx.x & 63;
    int wave = threadIdx.x >> 6;
    long rbase = (long)blockIdx.x * 64 + wave * 16;
    int r = lane & 15, kg = lane >> 4;
    facc acc[8];
#pragma unroll
    for (int t = 0; t < 8; ++t) acc[t] = (facc){0.f, 0.f, 0.f, 0.f};
    const bfrag* Ap = (const bfrag*)(A + (rbase + r) * K + kg * 8);
    const bfrag* Bq = (const bfrag*)Bp + lane;
#pragma unroll
    for (int ks = 0; ks < K / 32; ++ks) {
        bfrag a = Ap[ks * 4];
#pragma unroll
        for (int t = 0; t < 8; ++t) {
            bfrag b = Bq[(ks * 8 + t) * 64];
            acc[t] = __builtin_amdgcn_mfma_f32_16x16x32_bf16(a, b, acc[t], 0, 0, 0);
        }
    }
    long orow = rbase + kg * 4;
    int c = lane & 15;
    if (MODE == 0) {
        ushort* O = (ushort*)Out;
#pragma unroll
        for (int t = 0; t < 8; ++t)
#pragma unroll
            for (int j = 0; j < 4; ++j)
                O[(orow + j) * 128 + 16 * t + c] = f2bf(acc[t][j]);
    } else {
        float* O = (float*)Out;
#pragma unroll
        for (int j = 0; j < 4; ++j) {
            float ss = 0.f;
#pragma unroll
            for (int t = 0; t < 8; ++t) ss = fmaf(acc[t][j], acc[t][j], ss);
            ss += __shfl_xor(ss, 1);
            ss += __shfl_xor(ss, 2);
            ss += __shfl_xor(ss, 4);
            ss += __shfl_xor(ss, 8);
            float inv = 1.f / fmaxf(sqrtf(ss), 1e-12f);
#pragma unroll
            for (int t = 0; t < 8; ++t)
                O[(orow + j) * 128 + 16 * t + c] = acc[t][j] * inv;
        }
    }
}

// ---------------- SpMM: out[r] = alpha * sum_e w_e * in[col_e] + beta * prev[r] ----------------

template<int INBF, int HASPREV, int OUTBF>
__global__ __launch_bounds__(256) void spmm_k(const int* __restrict__ rp,
                                              const int2* __restrict__ csr,
                                              const void* __restrict__ in,
                                              const void* __restrict__ prev,
                                              void* __restrict__ out,
                                              float alpha, float beta) {
    int r = blockIdx.x * 4 + (threadIdx.x >> 6);
    int lane = threadIdx.x & 63;
    int s = rp[r], e1 = rp[r + 1];
    const float2* inf = (const float2*)in;
    const uint*   inb = (const uint*)in;
    float ax = 0.f, ay = 0.f, bx = 0.f, by = 0.f;
    int e = s;
    for (; e + 4 <= e1; e += 4) {
        int2 c0 = csr[e], c1 = csr[e + 1], c2 = csr[e + 2], c3 = csr[e + 3];
        float2 v0, v1, v2, v3;
        if (INBF) {
            uint u0 = inb[(long)c0.x * 64 + lane];
            uint u1 = inb[(long)c1.x * 64 + lane];
            uint u2 = inb[(long)c2.x * 64 + lane];
            uint u3 = inb[(long)c3.x * 64 + lane];
            v0 = make_float2(__uint_as_float(u0 << 16), __uint_as_float(u0 & 0xFFFF0000u));
            v1 = make_float2(__uint_as_float(u1 << 16), __uint_as_float(u1 & 0xFFFF0000u));
            v2 = make_float2(__uint_as_float(u2 << 16), __uint_as_float(u2 & 0xFFFF0000u));
            v3 = make_float2(__uint_as_float(u3 << 16), __uint_as_float(u3 & 0xFFFF0000u));
        } else {
            v0 = inf[(long)c0.x * 64 + lane];
            v1 = inf[(long)c1.x * 64 + lane];
            v2 = inf[(long)c2.x * 64 + lane];
            v3 = inf[(long)c3.x * 64 + lane];
        }
        float w0 = __int_as_float(c0.y), w1 = __int_as_float(c1.y);
        float w2 = __int_as_float(c2.y), w3 = __int_as_float(c3.y);
        ax = fmaf(w0, v0.x, ax); ay = fmaf(w0, v0.y, ay);
        bx = fmaf(w1, v1.x, bx); by = fmaf(w1, v1.y, by);
        ax = fmaf(w2, v2.x, ax); ay = fmaf(w2, v2.y, ay);
        bx = fmaf(w3, v3.x, bx); by = fmaf(w3, v3.y, by);
    }
    for (; e < e1; ++e) {
        int2 cw = csr[e];
        float wv = __int_as_float(cw.y);
        float2 v;
        if (INBF) {
            uint u = inb[(long)cw.x * 64 + lane];
            v = make_float2(__uint_as_float(u << 16), __uint_as_float(u & 0xFFFF0000u));
        } else {
            v = inf[(long)cw.x * 64 + lane];
        }
        ax = fmaf(wv, v.x, ax); ay = fmaf(wv, v.y, ay);
    }
    ax += bx; ay += by;
    float rx = alpha * ax, ry = alpha * ay;
    if (HASPREV) {
        uint pu = ((const uint*)prev)[(long)r * 64 + lane];
        rx = fmaf(beta, __uint_as_float(pu << 16), rx);
        ry = fmaf(beta, __uint_as_float(pu & 0xFFFF0000u), ry);
    }
    if (OUTBF) {
        ((uint*)out)[(long)r * 64 + lane] = (uint)f2bf(rx) | ((uint)f2bf(ry) << 16);
    } else {
        ((float2*)out)[(long)r * 64 + lane] = make_float2(rx, ry);
    }
}

// ---------------- batch stats (bf16 input) ----------------

__global__ __launch_bounds__(256) void stats_k(const ushort* __restrict__ buf,
                                               float* __restrict__ sum,
                                               float* __restrict__ sumsq) {
    int c = threadIdx.x & 127, half = threadIdx.x >> 7;
    int r0 = blockIdx.x * 128;
    int rend = r0 + 128; if (rend > NNODES) rend = NNODES;
    float s = 0.f, s2 = 0.f;
    for (int r = r0 + half; r < rend; r += 2) {
        float v = bf2f(buf[(long)r * 128 + c]);
        s += v;
        s2 = fmaf(v, v, s2);
    }
    __shared__ float sh[256], sh2[256];
    sh[threadIdx.x] = s; sh2[threadIdx.x] = s2;
    __syncthreads();
    if (threadIdx.x < 128) {
        atomicAdd(&sum[c],   sh[c]  + sh[c + 128]);
        atomicAdd(&sumsq[c], sh2[c] + sh2[c + 128]);
    }
}

__global__ void bnfin_k(const float* __restrict__ sum, const float* __restrict__ sumsq,
                        const float* __restrict__ g0, const float* __restrict__ be0,
                        const float* __restrict__ g1, const float* __restrict__ be1,
                        const float* __restrict__ g2, const float* __restrict__ be2,
                        float* __restrict__ bn) {
    int i = threadIdx.x;
    if (i >= 384) return;
    int s = i >> 7, c = i & 127;
    float mean = sum[i] * (1.f / NNODES);
    float var  = sumsq[i] * (1.f / NNODES) - mean * mean;
    const float* g = (s == 0) ? g0 : (s == 1) ? g1 : g2;
    const float* b = (s == 0) ? be0 : (s == 1) ? be1 : be2;
    float sc = g[c] * rsqrtf(var + 1e-5f);
    bn[s * 256 + c]       = sc;
    bn[s * 256 + 128 + c] = b[c] - mean * sc;
}

// ---------------- BN + PReLU + concat -> bf16 [N x 384] ----------------

__global__ __launch_bounds__(256) void bn_concat_k(const ushort* __restrict__ org,
                                                   const ushort* __restrict__ pos,
                                                   const ushort* __restrict__ neg,
                                                   const float* __restrict__ bn,
                                                   const float* __restrict__ prelu_w,
                                                   ushort* __restrict__ cb) {
    int idx = blockIdx.x * 256 + threadIdx.x;     // exactly 1,920,000 threads
    int r = idx / 48;
    int q = idx - r * 48;
    int s = q >> 4, w8 = q & 15;
    const ushort* src = (s == 0) ? org : (s == 1) ? pos : neg;
    float pw = prelu_w[0];
    int c0 = w8 * 8;
    uint4 u = *(const uint4*)(src + (long)r * 128 + c0);
    uint uu[4] = {u.x, u.y, u.z, u.w};
    uint oo[4];
#pragma unroll
    for (int k = 0; k < 4; ++k) {
        float vx = __uint_as_float(uu[k] << 16);
        float vy = __uint_as_float(uu[k] & 0xFFFF0000u);
        float scx = bn[s * 256 + c0 + 2 * k],       scy = bn[s * 256 + c0 + 2 * k + 1];
        float shx = bn[s * 256 + 128 + c0 + 2 * k], shy = bn[s * 256 + 128 + c0 + 2 * k + 1];
        float ox = fmaf(vx, scx, shx); ox = (ox >= 0.f) ? ox : pw * ox;
        float oy = fmaf(vy, scy, shy); oy = (oy >= 0.f) ? oy : pw * oy;
        oo[k] = (uint)f2bf(ox) | ((uint)f2bf(oy) << 16);
    }
    *(uint4*)(cb + (long)r * 384 + s * 128 + c0) = make_uint4(oo[0], oo[1], oo[2], oo[3]);
}

// ---------------- launch ----------------

extern "C" void kernel_launch(void* const* d_in, const int* in_sizes, int n_in,
                              void* d_out, int out_size, void* d_ws, size_t ws_size,
                              hipStream_t stream) {
    const float* x       = (const float*)d_in[0];
    const int*   pos_idx = (const int*)d_in[1];
    const float* pos_w   = (const float*)d_in[2];
    const int*   neg_idx = (const int*)d_in[3];
    const float* neg_w   = (const float*)d_in[4];
    const float* W_org   = (const float*)d_in[5];
    const float* W_pos   = (const float*)d_in[6];
    const float* W_neg   = (const float*)d_in[7];
    const float* g_org   = (const float*)d_in[8];
    const float* b_org   = (const float*)d_in[9];
    const float* g_pos   = (const float*)d_in[10];
    const float* b_pos   = (const float*)d_in[11];
    const float* g_neg   = (const float*)d_in[12];
    const float* b_neg   = (const float*)d_in[13];
    const float* prelu_w = (const float*)d_in[14];
    const float* W_mlp   = (const float*)d_in[15];
    float* out = (float*)d_out;

    char* ws = (char*)d_ws;
    const size_t FB = (size_t)NNODES * 128 * 2;       // 10,240,000 B per bf16 [N,128]
    ushort* org0b = (ushort*)(ws);
    ushort* p0b   = (ushort*)(ws + FB);
    ushort* n0b   = (ushort*)(ws + 2 * FB);
    ushort* xb    = (ushort*)(ws + 3 * FB);
    int2* csr_pos = (int2*)(ws + 4 * FB);
    int2* csr_neg = (int2*)(ws + 4 * FB + (size_t)NEDGE * 8);
    ushort* cb    = xb;                               // reuses xb+csr (dead by then): 30.72 MB
    char* base = ws + 3 * FB + (size_t)NNODES * 384 * 2;   // = ws + 61,440,000
    int* rp_pos  = (int*)base; base += 640064;
    int* rp_neg  = (int*)base; base += 640064;
    int* cur_pos = (int*)base; base += 640000;
    int* cur_neg = (int*)base; base += 640000;
    char* zbase = base;
    int* cnt_pos = (int*)base; base += 640000;
    int* cnt_neg = (int*)base; base += 640000;
    float* sums  = (float*)base; base += 1536;
    float* sumsq = (float*)base; base += 1536;
    float* bn    = (float*)base; base += 3072;
    ushort* Wb_org = (ushort*)base; base += 32768;
    ushort* Wb_pos = (ushort*)base; base += 32768;
    ushort* Wb_neg = (ushort*)base; base += 32768;
    ushort* Wb_mlp = (ushort*)base; base += 98304;
    float* t1 = out;                                  // fp32 SpMM scratch in d_out

    hipMemsetAsync(zbase, 0, 640000 * 2 + 1536 * 2, stream);

    count_rows_k<<<2500, 256, 0, stream>>>(pos_idx, cnt_pos, NEDGE);
    count_rows_k<<<2500, 256, 0, stream>>>(neg_idx, cnt_neg, NEDGE);
    exscan_k<<<1, 1024, 0, stream>>>(cnt_pos, rp_pos, cur_pos);
    exscan_k<<<1, 1024, 0, stream>>>(cnt_neg, rp_neg, cur_neg);
    scatter_k<<<2500, 256, 0, stream>>>(pos_idx, pos_idx + NEDGE, pos_w, cur_pos, csr_pos, NEDGE);
    scatter_k<<<2500, 256, 0, stream>>>(neg_idx, neg_idx + NEDGE, neg_w, cur_neg, csr_neg, NEDGE);

    cvt_bf16_k<<<2500, 256, 0, stream>>>(x, xb, 640000);
    pack_w_k<<<64, 256, 0, stream>>>(W_org, Wb_org, 128);
    pack_w_k<<<64, 256, 0, stream>>>(W_pos, Wb_pos, 128);
    pack_w_k<<<64, 256, 0, stream>>>(W_neg, Wb_neg, 128);
    pack_w_k<<<192, 256, 0, stream>>>(W_mlp, Wb_mlp, 384);

    mfma_gemm_k<128, 0><<<625, 256, 0, stream>>>(xb, Wb_org, org0b);
    mfma_gemm_k<128, 0><<<625, 256, 0, stream>>>(xb, Wb_pos, p0b);
    mfma_gemm_k<128, 0><<<625, 256, 0, stream>>>(xb, Wb_neg, n0b);

    stats_k<<<313, 256, 0, stream>>>(org0b, sums, sumsq);

    // Jacobi (a=b=1, K=3): x1 = 2*A@x0 ; x2 = 1.875*A@x1 - 1.6875*x0
    spmm_k<1, 0, 0><<<10000, 256, 0, stream>>>(rp_pos, csr_pos, p0b, nullptr, t1, 2.0f, 0.f);
    spmm_k<0, 1, 1><<<10000, 256, 0, stream>>>(rp_pos, csr_pos, t1, p0b, p0b, 1.875f, -1.6875f);
    stats_k<<<313, 256, 0, stream>>>(p0b, sums + 128, sumsq + 128);

    spmm_k<1, 0, 0><<<10000, 256, 0, stream>>>(rp_neg, csr_neg, n0b, nullptr, t1, 2.0f, 0.f);
    spmm_k<0, 1, 1><<<10000, 256, 0, stream>>>(rp_neg, csr_neg, t1, n0b, n0b, 1.875f, -1.6875f);
    stats_k<<<313, 256, 0, stream>>>(n0b, sums + 256, sumsq + 256);

    bnfin_k<<<1, 384, 0, stream>>>(sums, sumsq, g_org, b_org, g_pos, b_pos, g_neg, b_neg, bn);
    bn_concat_k<<<7500, 256, 0, stream>>>(org0b, p0b, n0b, bn, prelu_w, cb);
    mfma_gemm_k<384, 1><<<625, 256, 0, stream>>>(cb, Wb_mlp, out);

    (void)in_sizes; (void)n_in; (void)out_size; (void)ws_size;
}

// Round 3
// 410.844 us; speedup vs baseline: 3.6219x; 1.3757x over previous
//
#include <hip/hip_runtime.h>

#define NNODES 40000
#define NEDGE  640000
#define SBLK   157        // ceil(40000/256)

typedef __attribute__((ext_vector_type(8))) short bfrag;
typedef __attribute__((ext_vector_type(4))) float facc;

__device__ inline ushort f2bf(float f) {
    uint u = __float_as_uint(f);
    return (ushort)((u + 0x7FFFu + ((u >> 16) & 1u)) >> 16);
}
__device__ inline float bf2f(ushort h) {
    return __uint_as_float(((uint)h) << 16);
}

// ---------------- CSR build ----------------

__global__ __launch_bounds__(256) void count2_k(const int* __restrict__ pos_rows,
                                                const int* __restrict__ neg_rows,
                                                int* __restrict__ cnt) {
    int b = blockIdx.x;
    int seg = (b >= 2500);
    int i = (b - seg * 2500) * 256 + threadIdx.x;     // always < NEDGE (2500*256==NEDGE)
    const int* rows = seg ? neg_rows : pos_rows;
    atomicAdd(&cnt[seg * NNODES + rows[i]], 1);
}

// per-block inclusive scan; block totals to part
__global__ __launch_bounds__(256) void scan_local_k(const int* __restrict__ cnt,
                                                    int* __restrict__ tmp,
                                                    int* __restrict__ part) {
    int b = blockIdx.x;                // 0..2*SBLK-1
    int seg = (b >= SBLK);
    int li = (b - seg * SBLK) * 256 + threadIdx.x;
    int gi = seg * NNODES + li;
    int v = (li < NNODES) ? cnt[gi] : 0;
    int lane = threadIdx.x & 63, w = threadIdx.x >> 6;
    int s = v;
#pragma unroll
    for (int off = 1; off < 64; off <<= 1) {
        int t = __shfl_up(s, off);
        if (lane >= off) s += t;
    }
    __shared__ int wt[4];
    if (lane == 63) wt[w] = s;
    __syncthreads();
#pragma unroll
    for (int i = 0; i < 3; ++i) if (w > i) s += wt[i];
    if (li < NNODES) tmp[gi] = s;
    if (threadIdx.x == 255) part[b] = s;
}

// exclusive-scan the SBLK partials of each segment (grid = 2)
__global__ __launch_bounds__(256) void scan_part_k(int* __restrict__ part) {
    int seg = blockIdx.x;
    int t = threadIdx.x;
    int v = (t < SBLK) ? part[seg * SBLK + t] : 0;
    int lane = t & 63, w = t >> 6;
    int s = v;
#pragma unroll
    for (int off = 1; off < 64; off <<= 1) {
        int x = __shfl_up(s, off);
        if (lane >= off) s += x;
    }
    __shared__ int wt[4];
    if (lane == 63) wt[w] = s;
    __syncthreads();
#pragma unroll
    for (int i = 0; i < 3; ++i) if (w > i) s += wt[i];
    if (t < SBLK) part[seg * SBLK + t] = s - v;        // exclusive
}

__global__ __launch_bounds__(256) void scan_add_k(const int* __restrict__ cnt,
                                                  const int* __restrict__ tmp,
                                                  const int* __restrict__ part,
                                                  int* __restrict__ rp_pos,
                                                  int* __restrict__ rp_neg,
                                                  int* __restrict__ cur) {
    int b = blockIdx.x;
    int seg = (b >= SBLK);
    int li = (b - seg * SBLK) * 256 + threadIdx.x;
    if (li >= NNODES) return;
    int gi = seg * NNODES + li;
    int excl = tmp[gi] - cnt[gi] + part[b];
    int* rp = seg ? rp_neg : rp_pos;
    rp[li] = excl;
    cur[gi] = excl;
    if (li == 0) rp[NNODES] = NEDGE;
}

__global__ __launch_bounds__(256) void scatter2_k(const int* __restrict__ pos_idx,
                                                  const float* __restrict__ pos_w,
                                                  const int* __restrict__ neg_idx,
                                                  const float* __restrict__ neg_w,
                                                  int* __restrict__ cur,
                                                  int2* __restrict__ csr_pos,
                                                  int2* __restrict__ csr_neg) {
    int b = blockIdx.x;
    int seg = (b >= 2500);
    int e = (b - seg * 2500) * 256 + threadIdx.x;
    const int* idx = seg ? neg_idx : pos_idx;
    const float* w = seg ? neg_w : pos_w;
    int2* csr = seg ? csr_neg : csr_pos;
    int r = idx[e];
    int p = atomicAdd(&cur[seg * NNODES + r], 1);
    csr[p] = make_int2(idx[NEDGE + e], __float_as_int(w[e]));
}

// ---------------- fp32 -> bf16 conversion ----------------

__global__ __launch_bounds__(256) void cvt_bf16_k(const float* __restrict__ in,
                                                  ushort* __restrict__ out, int n8) {
    int i = blockIdx.x * 256 + threadIdx.x;
    if (i >= n8) return;
    const float4* p = (const float4*)(in + (long)i * 8);
    float4 a = p[0], b = p[1];
    uint4 o;
    o.x = (uint)f2bf(a.x) | ((uint)f2bf(a.y) << 16);
    o.y = (uint)f2bf(a.z) | ((uint)f2bf(a.w) << 16);
    o.z = (uint)f2bf(b.x) | ((uint)f2bf(b.y) << 16);
    o.w = (uint)f2bf(b.z) | ((uint)f2bf(b.w) << 16);
    ((uint4*)out)[i] = o;
}

// ---------------- pack all W into MFMA B-fragment order ----------------
// frag layout: elem j of lane l for (k-step ks, n-tile t):
//   B[k = ks*32 + (l>>4)*8 + j][c = (l&15) + 16*t]

__global__ __launch_bounds__(256) void pack_all_k(const float* __restrict__ Wo,
                                                  const float* __restrict__ Wp,
                                                  const float* __restrict__ Wn,
                                                  const float* __restrict__ Wm,
                                                  ushort* __restrict__ out) {
    int idx = blockIdx.x * 256 + threadIdx.x;      // 0..98303
    const float* W;
    ushort* dst;
    int local;
    if (idx < 49152) {
        int m = idx >> 14;
        local = idx & 16383;
        W = (m == 0) ? Wo : (m == 1) ? Wp : Wn;
        dst = out + m * 16384;
    } else {
        local = idx - 49152;
        W = Wm;
        dst = out + 49152;
    }
    int j = local & 7, l = (local >> 3) & 63, t = (local >> 9) & 7, ks = local >> 12;
    int k = ks * 32 + (l >> 4) * 8 + j;
    int c = (l & 15) + 16 * t;
    dst[local] = f2bf(W[k * 128 + c]);
}

// ---------------- fused triple MFMA GEMM: xb @ {W_org,W_pos,W_neg} ----------------

__global__ __launch_bounds__(256) void mfma_gemm3_k(const ushort* __restrict__ A,
                                                    const ushort* __restrict__ B0,
                                                    const ushort* __restrict__ B1,
                                                    const ushort* __restrict__ B2,
                                                    ushort* __restrict__ O0,
                                                    ushort* __restrict__ O1,
                                                    ushort* __restrict__ O2) {
    int lane = threadIdx.x & 63, wave = threadIdx.x >> 6;
    long rbase = (long)blockIdx.x * 64 + wave * 16;
    int r = lane & 15, kg = lane >> 4;
    const bfrag* Ap = (const bfrag*)(A + (rbase + r) * 128 + kg * 8);
    bfrag a[4];
#pragma unroll
    for (int ks = 0; ks < 4; ++ks) a[ks] = Ap[ks * 4];
    const ushort* Bs[3] = {B0, B1, B2};
    ushort* Os[3] = {O0, O1, O2};
    long orow = rbase + kg * 4;
#pragma unroll
    for (int m = 0; m < 3; ++m) {
        const bfrag* Bq = (const bfrag*)Bs[m] + lane;
        facc acc[8];
#pragma unroll
        for (int t = 0; t < 8; ++t) acc[t] = (facc){0.f, 0.f, 0.f, 0.f};
#pragma unroll
        for (int ks = 0; ks < 4; ++ks)
#pragma unroll
            for (int t = 0; t < 8; ++t)
                acc[t] = __builtin_amdgcn_mfma_f32_16x16x32_bf16(a[ks], Bq[(ks * 8 + t) * 64], acc[t], 0, 0, 0);
        ushort* O = Os[m];
#pragma unroll
        for (int t = 0; t < 8; ++t)
#pragma unroll
            for (int j = 0; j < 4; ++j)
                O[(orow + j) * 128 + 16 * t + r] = f2bf(acc[t][j]);
    }
}

// ---------------- final MFMA GEMM K=384 + fused row-L2-normalize ----------------

__global__ __launch_bounds__(256) void mfma_gemm_mlp_k(const ushort* __restrict__ A,
                                                       const ushort* __restrict__ Bp,
                                                       float* __restrict__ Out) {
    int lane = threadIdx.x & 63, wave = threadIdx.x >> 6;
    long rbase = (long)blockIdx.x * 64 + wave * 16;
    int r = lane & 15, kg = lane >> 4;
    facc acc[8];
#pragma unroll
    for (int t = 0; t < 8; ++t) acc[t] = (facc){0.f, 0.f, 0.f, 0.f};
    const bfrag* Ap = (const bfrag*)(A + (rbase + r) * 384 + kg * 8);
    const bfrag* Bq = (const bfrag*)Bp + lane;
#pragma unroll
    for (int ks = 0; ks < 12; ++ks) {
        bfrag a = Ap[ks * 4];
#pragma unroll
        for (int t = 0; t < 8; ++t)
            acc[t] = __builtin_amdgcn_mfma_f32_16x16x32_bf16(a, Bq[(ks * 8 + t) * 64], acc[t], 0, 0, 0);
    }
    long orow = rbase + kg * 4;
#pragma unroll
    for (int j = 0; j < 4; ++j) {
        float ss = 0.f;
#pragma unroll
        for (int t = 0; t < 8; ++t) ss = fmaf(acc[t][j], acc[t][j], ss);
        ss += __shfl_xor(ss, 1);
        ss += __shfl_xor(ss, 2);
        ss += __shfl_xor(ss, 4);
        ss += __shfl_xor(ss, 8);
        float inv = 1.f / fmaxf(sqrtf(ss), 1e-12f);
#pragma unroll
        for (int t = 0; t < 8; ++t)
            Out[(orow + j) * 128 + 16 * t + r] = acc[t][j] * inv;
    }
}

// ---------------- SpMM: out[r] = alpha * sum_e w_e * in[col_e] + beta * prev[r] ----------------
// all feature buffers bf16

template<int HASPREV>
__global__ __launch_bounds__(256) void spmm_k(const int* __restrict__ rp,
                                              const int2* __restrict__ csr,
                                              const uint* __restrict__ in,
                                              const uint* __restrict__ prev,
                                              uint* __restrict__ out,
                                              float alpha, float beta) {
    int r = blockIdx.x * 4 + (threadIdx.x >> 6);
    int lane = threadIdx.x & 63;
    int s = rp[r], e1 = rp[r + 1];
    float ax = 0.f, ay = 0.f, bx = 0.f, by = 0.f;
    int e = s;
    for (; e + 4 <= e1; e += 4) {
        int2 c0 = csr[e], c1 = csr[e + 1], c2 = csr[e + 2], c3 = csr[e + 3];
        uint u0 = in[(long)c0.x * 64 + lane];
        uint u1 = in[(long)c1.x * 64 + lane];
        uint u2 = in[(long)c2.x * 64 + lane];
        uint u3 = in[(long)c3.x * 64 + lane];
        float w0 = __int_as_float(c0.y), w1 = __int_as_float(c1.y);
        float w2 = __int_as_float(c2.y), w3 = __int_as_float(c3.y);
        ax = fmaf(w0, __uint_as_float(u0 << 16), ax); ay = fmaf(w0, __uint_as_float(u0 & 0xFFFF0000u), ay);
        bx = fmaf(w1, __uint_as_float(u1 << 16), bx); by = fmaf(w1, __uint_as_float(u1 & 0xFFFF0000u), by);
        ax = fmaf(w2, __uint_as_float(u2 << 16), ax); ay = fmaf(w2, __uint_as_float(u2 & 0xFFFF0000u), ay);
        bx = fmaf(w3, __uint_as_float(u3 << 16), bx); by = fmaf(w3, __uint_as_float(u3 & 0xFFFF0000u), by);
    }
    for (; e < e1; ++e) {
        int2 cw = csr[e];
        float wv = __int_as_float(cw.y);
        uint u = in[(long)cw.x * 64 + lane];
        ax = fmaf(wv, __uint_as_float(u << 16), ax);
        ay = fmaf(wv, __uint_as_float(u & 0xFFFF0000u), ay);
    }
    ax += bx; ay += by;
    float rx = alpha * ax, ry = alpha * ay;
    if (HASPREV) {
        uint pu = prev[(long)r * 64 + lane];
        rx = fmaf(beta, __uint_as_float(pu << 16), rx);
        ry = fmaf(beta, __uint_as_float(pu & 0xFFFF0000u), ry);
    }
    out[(long)r * 64 + lane] = (uint)f2bf(rx) | ((uint)f2bf(ry) << 16);
}

// ---------------- batch stats (bf16 input) ----------------

__global__ __launch_bounds__(256) void stats_k(const ushort* __restrict__ buf,
                                               float* __restrict__ sum,
                                               float* __restrict__ sumsq) {
    int c = threadIdx.x & 127, half = threadIdx.x >> 7;
    int r0 = blockIdx.x * 128;
    int rend = r0 + 128; if (rend > NNODES) rend = NNODES;
    float s = 0.f, s2 = 0.f;
    for (int r = r0 + half; r < rend; r += 2) {
        float v = bf2f(buf[(long)r * 128 + c]);
        s += v;
        s2 = fmaf(v, v, s2);
    }
    __shared__ float sh[256], sh2[256];
    sh[threadIdx.x] = s; sh2[threadIdx.x] = s2;
    __syncthreads();
    if (threadIdx.x < 128) {
        atomicAdd(&sum[c],   sh[c]  + sh[c + 128]);
        atomicAdd(&sumsq[c], sh2[c] + sh2[c + 128]);
    }
}

__global__ void bnfin_k(const float* __restrict__ sum, const float* __restrict__ sumsq,
                        const float* __restrict__ g0, const float* __restrict__ be0,
                        const float* __restrict__ g1, const float* __restrict__ be1,
                        const float* __restrict__ g2, const float* __restrict__ be2,
                        float* __restrict__ bn) {
    int i = threadIdx.x;
    if (i >= 384) return;
    int s = i >> 7, c = i & 127;
    float mean = sum[i] * (1.f / NNODES);
    float var  = sumsq[i] * (1.f / NNODES) - mean * mean;
    const float* g = (s == 0) ? g0 : (s == 1) ? g1 : g2;
    const float* b = (s == 0) ? be0 : (s == 1) ? be1 : be2;
    float sc = g[c] * rsqrtf(var + 1e-5f);
    bn[s * 256 + c]       = sc;
    bn[s * 256 + 128 + c] = b[c] - mean * sc;
}

// ---------------- BN + PReLU + concat -> bf16 [N x 384] ----------------

__global__ __launch_bounds__(256) void bn_concat_k(const ushort* __restrict__ org,
                                                   const ushort* __restrict__ pos,
                                                   const ushort* __restrict__ neg,
                                                   const float* __restrict__ bn,
                                                   const float* __restrict__ prelu_w,
                                                   ushort* __restrict__ cb) {
    int idx = blockIdx.x * 256 + threadIdx.x;     // 1,920,000 threads
    int r = idx / 48;
    int q = idx - r * 48;
    int s = q >> 4, w8 = q & 15;
    const ushort* src = (s == 0) ? org : (s == 1) ? pos : neg;
    float pw = prelu_w[0];
    int c0 = w8 * 8;
    uint4 u = *(const uint4*)(src + (long)r * 128 + c0);
    uint uu[4] = {u.x, u.y, u.z, u.w};
    uint oo[4];
#pragma unroll
    for (int k = 0; k < 4; ++k) {
        float vx = __uint_as_float(uu[k] << 16);
        float vy = __uint_as_float(uu[k] & 0xFFFF0000u);
        float scx = bn[s * 256 + c0 + 2 * k],       scy = bn[s * 256 + c0 + 2 * k + 1];
        float shx = bn[s * 256 + 128 + c0 + 2 * k], shy = bn[s * 256 + 128 + c0 + 2 * k + 1];
        float ox = fmaf(vx, scx, shx); ox = (ox >= 0.f) ? ox : pw * ox;
        float oy = fmaf(vy, scy, shy); oy = (oy >= 0.f) ? oy : pw * oy;
        oo[k] = (uint)f2bf(ox) | ((uint)f2bf(oy) << 16);
    }
    *(uint4*)(cb + (long)r * 384 + s * 128 + c0) = make_uint4(oo[0], oo[1], oo[2], oo[3]);
}

// ---------------- launch ----------------

extern "C" void kernel_launch(void* const* d_in, const int* in_sizes, int n_in,
                              void* d_out, int out_size, void* d_ws, size_t ws_size,
                              hipStream_t stream) {
    const float* x       = (const float*)d_in[0];
    const int*   pos_idx = (const int*)d_in[1];
    const float* pos_w   = (const float*)d_in[2];
    const int*   neg_idx = (const int*)d_in[3];
    const float* neg_w   = (const float*)d_in[4];
    const float* W_org   = (const float*)d_in[5];
    const float* W_pos   = (const float*)d_in[6];
    const float* W_neg   = (const float*)d_in[7];
    const float* g_org   = (const float*)d_in[8];
    const float* b_org   = (const float*)d_in[9];
    const float* g_pos   = (const float*)d_in[10];
    const float* b_pos   = (const float*)d_in[11];
    const float* g_neg   = (const float*)d_in[12];
    const float* b_neg   = (const float*)d_in[13];
    const float* prelu_w = (const float*)d_in[14];
    const float* W_mlp   = (const float*)d_in[15];
    float* out = (float*)d_out;

    char* ws = (char*)d_ws;
    const size_t FB = (size_t)NNODES * 128 * 2;       // 10,240,000 B
    ushort* org0b = (ushort*)(ws);
    ushort* p0b   = (ushort*)(ws + FB);
    ushort* n0b   = (ushort*)(ws + 2 * FB);
    ushort* xb    = (ushort*)(ws + 3 * FB);
    int2* csr_pos = (int2*)(ws + 4 * FB);
    int2* csr_neg = (int2*)(ws + 4 * FB + (size_t)NEDGE * 8);
    ushort* cb    = xb;                               // spans xb+csr (dead by then), 30.72 MB
    char* base = ws + 61440000;
    int* rp_pos = (int*)base; base += 160064;
    int* rp_neg = (int*)base; base += 160064;
    int* cur    = (int*)base; base += 320000;         // [2*NNODES]
    int* tmp    = (int*)base; base += 320000;         // scan scratch
    int* part   = (int*)base; base += 1280;           // 314 partials
    char* zbase = base;
    int* cnt    = (int*)base; base += 320000;         // [2*NNODES]
    float* sums  = (float*)base; base += 1536;
    float* sumsq = (float*)base; base += 1536;
    float* bn    = (float*)base; base += 3072;
    ushort* Wb   = (ushort*)base; base += 196608;     // org(16384) pos(16384) neg(16384) mlp(49152)
    uint* t1b = (uint*)d_out;                         // bf16 SpMM scratch in d_out

    hipMemsetAsync(zbase, 0, 320000 + 1536 * 2, stream);

    count2_k<<<5000, 256, 0, stream>>>(pos_idx, neg_idx, cnt);
    scan_local_k<<<2 * SBLK, 256, 0, stream>>>(cnt, tmp, part);
    scan_part_k<<<2, 256, 0, stream>>>(part);
    scan_add_k<<<2 * SBLK, 256, 0, stream>>>(cnt, tmp, part, rp_pos, rp_neg, cur);
    scatter2_k<<<5000, 256, 0, stream>>>(pos_idx, pos_w, neg_idx, neg_w, cur, csr_pos, csr_neg);

    cvt_bf16_k<<<2500, 256, 0, stream>>>(x, xb, 640000);
    pack_all_k<<<384, 256, 0, stream>>>(W_org, W_pos, W_neg, W_mlp, Wb);

    mfma_gemm3_k<<<625, 256, 0, stream>>>(xb, Wb, Wb + 16384, Wb + 32768, org0b, p0b, n0b);
    stats_k<<<313, 256, 0, stream>>>(org0b, sums, sumsq);

    // Jacobi (a=b=1, K=3): x1 = 2*A@x0 ; x2 = 1.875*A@x1 - 1.6875*x0
    spmm_k<0><<<10000, 256, 0, stream>>>(rp_pos, csr_pos, (const uint*)p0b, nullptr, t1b, 2.0f, 0.f);
    spmm_k<1><<<10000, 256, 0, stream>>>(rp_pos, csr_pos, t1b, (const uint*)p0b, (uint*)p0b, 1.875f, -1.6875f);
    stats_k<<<313, 256, 0, stream>>>(p0b, sums + 128, sumsq + 128);

    spmm_k<0><<<10000, 256, 0, stream>>>(rp_neg, csr_neg, (const uint*)n0b, nullptr, t1b, 2.0f, 0.f);
    spmm_k<1><<<10000, 256, 0, stream>>>(rp_neg, csr_neg, t1b, (const uint*)n0b, (uint*)n0b, 1.875f, -1.6875f);
    stats_k<<<313, 256, 0, stream>>>(n0b, sums + 256, sumsq + 256);

    bnfin_k<<<1, 384, 0, stream>>>(sums, sumsq, g_org, b_org, g_pos, b_pos, g_neg, b_neg, bn);
    bn_concat_k<<<7500, 256, 0, stream>>>(org0b, p0b, n0b, bn, prelu_w, cb);
    mfma_gemm_mlp_k<<<625, 256, 0, stream>>>(cb, Wb + 49152, out);

    (void)in_sizes; (void)n_in; (void)out_size; (void)ws_size;
}